// Round 3
// baseline (2018.891 us; speedup 1.0000x reference)
//
#include <hip/hip_runtime.h>
#include <hip/hip_bf16.h>

#define Bsz 32
#define Ssz 128
#define Tsz 64
#define TD  63           // decoder steps
#define NSTEP 191        // Ssz + TD
#define Esz 128
#define Hsz 256
#define G4  1024         // 4*H
#define Vsz 32000
#define NB  16           // participating recurrence blocks
#define NBL 128          // launched blocks (round-robin over 8 XCDs)
#define SENT32 0xFFC1FFC1u   // 2x bf16 NaN — unreachable as packed h pair
#define SLOW_AFTER 12    // fast-poll rounds before agent-scope fallback

typedef __attribute__((ext_vector_type(8))) short short8;
typedef __attribute__((ext_vector_type(4))) float f32x4;

__device__ __forceinline__ unsigned short f2bf(float f) {
    union { float f; unsigned u; } v; v.f = f;
    unsigned u = v.u;
    unsigned r = u + 0x7FFFu + ((u >> 16) & 1u);   // RNE
    return (unsigned short)(r >> 16);
}

__device__ __forceinline__ float rcpf(float x) { return __builtin_amdgcn_rcpf(x); }
__device__ __forceinline__ float sigm(float x) { return rcpf(1.f + __expf(-x)); }
// tanh(x) = 1 - 2/(e^{2x}+1); saturates correctly at +-inf
__device__ __forceinline__ float tanh_fast(float x) { return 1.f - 2.f * rcpf(1.f + __expf(2.f * x)); }

__device__ __forceinline__ bool bad4(uint4 v) {
    return (v.x == SENT32) | (v.y == SENT32) | (v.z == SENT32) | (v.w == SENT32);
}

// ---------------------------------------------------------------------------
// K0: convert Wfc fp32 -> bf16 in workspace
// ---------------------------------------------------------------------------
__global__ void k_cvt(const float* __restrict__ src, unsigned short* __restrict__ dst, long n) {
    long i = (long)blockIdx.x * blockDim.x + threadIdx.x;
    long base = i * 8;
    if (base >= n) return;
    float4 f0 = ((const float4*)(src + base))[0];
    float4 f1 = ((const float4*)(src + base))[1];
    union { unsigned short u[8]; uint4 v; } r;
    r.u[0] = f2bf(f0.x); r.u[1] = f2bf(f0.y); r.u[2] = f2bf(f0.z); r.u[3] = f2bf(f0.w);
    r.u[4] = f2bf(f1.x); r.u[5] = f2bf(f1.y); r.u[6] = f2bf(f1.z); r.u[7] = f2bf(f1.w);
    *(uint4*)(dst + base) = r.v;
}

// ---------------------------------------------------------------------------
// K1: xW[t][b][g] = emb[token(t,b)] @ Wih^T + bias  for all 191 steps.
// grid (16, 191). Also initializes BOTH h dataflow buffers (fast: polled via
// L2 sc0 loads; slow: agent-scope fallback): slot 0 = h_0 zeros, slots
// 1..191 = SENTINEL. Agent-scope stores land at L3; k_recur's dispatch-
// boundary acquire invalidates L2 so first sc0 touch refetches from L3.
// ---------------------------------------------------------------------------
__global__ void __launch_bounds__(256) k_input(
        const int* __restrict__ src, const int* __restrict__ trg,
        const float* __restrict__ emb_src, const float* __restrict__ emb_trg,
        const float* __restrict__ Wih_e, const float* __restrict__ Wih_d,
        const float* __restrict__ b_e, const float* __restrict__ b_d,
        float* __restrict__ xW, unsigned* __restrict__ hF, unsigned* __restrict__ hS) {
    const int t = blockIdx.y;
    const int nb = blockIdx.x;
    const int tid = threadIdx.x;
    const bool enc = (t < Ssz);
    const float* emb  = enc ? emb_src : emb_trg;
    const float* Wih  = enc ? Wih_e : Wih_d;
    const float* bias = enc ? b_e : b_d;

    __shared__ unsigned short a_lds[32][Esz + 8];   // [32][136] bf16

    {   // stage embedding rows (bf16) for the 32 batch elements
        int b = tid >> 3, seg = tid & 7;
        int tok = enc ? src[b * Ssz + t] : trg[b * Tsz + (t - Ssz)];
        const float* row = emb + (long)tok * Esz + seg * 16;
        #pragma unroll
        for (int i = 0; i < 16; ++i)
            a_lds[b][seg * 16 + i] = f2bf(row[i]);
    }
    // sentinel-fill slot t+1 of both buffers (16 blocks x 256 thr = 1 slot)
    __hip_atomic_store(&hF[(t + 1) * 4096 + nb * 256 + tid], SENT32,
                       __ATOMIC_RELAXED, __HIP_MEMORY_SCOPE_AGENT);
    __hip_atomic_store(&hS[(t + 1) * 4096 + nb * 256 + tid], SENT32,
                       __ATOMIC_RELAXED, __HIP_MEMORY_SCOPE_AGENT);
    if (t == 0) {   // slot 0 (h_0 = zeros)
        __hip_atomic_store(&hF[nb * 256 + tid], 0u, __ATOMIC_RELAXED, __HIP_MEMORY_SCOPE_AGENT);
        __hip_atomic_store(&hS[nb * 256 + tid], 0u, __ATOMIC_RELAXED, __HIP_MEMORY_SCOPE_AGENT);
    }
    __syncthreads();

    const int w = tid >> 6, l = tid & 63;
    const int n = l & 15, q = l >> 4;
    const int col = nb * 64 + w * 16 + n;           // 0..1023

    short8 bw[4];
    #pragma unroll
    for (int kt = 0; kt < 4; ++kt) {
        const float* wr = Wih + (long)col * Esz + kt * 32 + q * 8;
        short8 f;
        #pragma unroll
        for (int i = 0; i < 8; ++i) f[i] = (short)f2bf(wr[i]);
        bw[kt] = f;
    }
    f32x4 acc0 = {0.f,0.f,0.f,0.f}, acc1 = {0.f,0.f,0.f,0.f};
    #pragma unroll
    for (int kt = 0; kt < 4; ++kt) {
        int k0 = kt * 32 + q * 8;
        short8 a0 = *(const short8*)&a_lds[n][k0];
        short8 a1 = *(const short8*)&a_lds[16 + n][k0];
        acc0 = __builtin_amdgcn_mfma_f32_16x16x32_bf16(a0, bw[kt], acc0, 0, 0, 0);
        acc1 = __builtin_amdgcn_mfma_f32_16x16x32_bf16(a1, bw[kt], acc1, 0, 0, 0);
    }
    float bv = bias[col];
    float* o = xW + (long)t * (Bsz * G4);
    #pragma unroll
    for (int r = 0; r < 4; ++r) {
        int m = q * 4 + r;
        o[m * G4 + col]        = acc0[r] + bv;
        o[(16 + m) * G4 + col] = acc1[r] + bv;
    }
}

// ---------------------------------------------------------------------------
// K2: LSTM recurrence — SINGLE-XCD L2-coherent sentinel dataflow.
//
// Placement: 128 blocks launched; only blockIdx%8==0 participate (round-
// robin workgroup->XCD mapping puts all 16 on XCD0, 1 CU each). Exchange:
//   producer: PLAIN dword store of packed h (L1 is write-through -> lands
//             in the shared XCD L2, ~100cy), plus agent-scope mirror store
//             into the slow buffer (L3) for the fallback path.
//   consumer: global_load_dwordx4 ... sc0 (bypass L1, read L2 coherently,
//             ~200cy RTT) polling the sentinel; BATCHED retry — reissue all
//             pending loads per round, ONE vmcnt(0) per round (fixes r2's
//             serial per-element retry = up to 8 dependent ~700cy agent
//             RTTs/step). After SLOW_AFTER rounds, fall back to agent-scope
//             loads of the slow buffer (covers broken placement: correct,
//             just r2-speed). sched_barrier(0) after each asm waitcnt so
//             the sentinel check can't be hoisted above it (rule #18).
// Slots never reused (192 of them) -> no ABA; stores monotone -> no
// livelock. One __syncthreads per step (h_lds double-buffered: a wave can
// only reach staging of step s+2 after all waves ds_read step s).
// ---------------------------------------------------------------------------
__global__ void __launch_bounds__(256, 1) k_recur(
        const float* __restrict__ Whh_e, const float* __restrict__ Whh_d,
        const float* __restrict__ xW, unsigned* __restrict__ hF,
        unsigned* __restrict__ hS, unsigned* __restrict__ hs_dw,
        float* __restrict__ out_tail) {
    if (blockIdx.x & 7) return;                // keep only XCD0 residents
    const int nb = blockIdx.x >> 3;            // 0..15
    const int tid = threadIdx.x;
    const int w = tid >> 6, l = tid & 63;
    const int n = l & 15, q = l >> 4;          // MFMA lane coords
    const int p = (l >> 2) & 3, g = l & 3;     // gate-col n = 4*p + g
    const int JB = nb * 16 + w * 4;            // wave's h-columns JB..JB+3

    __shared__ unsigned short h_lds[2][32][Hsz + 8];  // dbuf, row = 528 B
    __shared__ float glds[4][16][35];                 // wave-private transpose

    // Weights in registers: B fragment for gate-col n=(p,g) = Whh row g*256+JB+p
    short8 be[8], bd[8];
    {
        const int R = g * Hsz + JB + p;
        #pragma unroll
        for (int kt = 0; kt < 8; ++kt) {
            const float* we = Whh_e + (long)R * Hsz + kt * 32 + q * 8;
            const float* wd = Whh_d + (long)R * Hsz + kt * 32 + q * 8;
            short8 fe, fd;
            #pragma unroll
            for (int i = 0; i < 8; ++i) { fe[i] = (short)f2bf(we[i]); fd[i] = (short)f2bf(wd[i]); }
            be[kt] = fe; bd[kt] = fd;
        }
    }

    // pointwise cells: lane handles (batch m, cols jc, jc+1); jc even.
    const int m = l >> 1, c0 = (l & 1) * 2, jc = JB + c0;
    float cc0 = 0.f, cc1 = 0.f;

    for (int s = 0; s < NSTEP; ++s) {
        // A: prefetch this lane's x-gates (plain cached; hides under poll)
        const float* xrow = xW + (long)s * (Bsz * G4) + m * G4 + jc;
        float2 xg0 = *(const float2*)(xrow + 0 * Hsz);
        float2 xg1 = *(const float2*)(xrow + 1 * Hsz);
        float2 xg2 = *(const float2*)(xrow + 2 * Hsz);
        float2 xg3 = *(const float2*)(xrow + 3 * Hsz);

        // B: poll-stage slot s into h_lds[s&1]. 1024 uint4 / 256 threads.
        char* const ldsb = (char*)&h_lds[s & 1][0][0];
        const char* fbase = (const char*)(hF + (long)s * 4096);
        const char* sbase = (const char*)(hS + (long)s * 4096);
        uint4 v[4];
        #pragma unroll
        for (int i = 0; i < 4; ++i)
            asm volatile("global_load_dwordx4 %0, %1, off sc0"
                         : "=v"(v[i]) : "v"(fbase + (i * 256 + tid) * 16));
        asm volatile("s_waitcnt vmcnt(0)" ::: "memory");
        __builtin_amdgcn_sched_barrier(0);

        unsigned pend = 0;
        #pragma unroll
        for (int i = 0; i < 4; ++i) {
            if (bad4(v[i])) pend |= 1u << i;
            else {
                int d4 = i * 256 + tid;
                *(uint4*)(ldsb + (d4 >> 5) * 528 + (d4 & 31) * 16) = v[i];
            }
        }
        int rounds = 0;
        while (__builtin_expect(pend != 0, 0)) {
            ++rounds;
            if (rounds <= SLOW_AFTER) {
                #pragma unroll
                for (int i = 0; i < 4; ++i)
                    if (pend & (1u << i))
                        asm volatile("global_load_dwordx4 %0, %1, off sc0"
                                     : "=v"(v[i]) : "v"(fbase + (i * 256 + tid) * 16));
                asm volatile("s_waitcnt vmcnt(0)" ::: "memory");
                __builtin_amdgcn_sched_barrier(0);
            } else {
                // fallback: agent-scope (L2-bypass) loads of the slow mirror
                #pragma unroll
                for (int i = 0; i < 4; ++i)
                    if (pend & (1u << i)) {
                        const unsigned long long* sp =
                            (const unsigned long long*)(sbase + (i * 256 + tid) * 16);
                        union { unsigned long long u[2]; uint4 q4; } t;
                        t.u[0] = __hip_atomic_load(sp,     __ATOMIC_RELAXED, __HIP_MEMORY_SCOPE_AGENT);
                        t.u[1] = __hip_atomic_load(sp + 1, __ATOMIC_RELAXED, __HIP_MEMORY_SCOPE_AGENT);
                        v[i] = t.q4;
                    }
            }
            #pragma unroll
            for (int i = 0; i < 4; ++i)
                if ((pend & (1u << i)) && !bad4(v[i])) {
                    int d4 = i * 256 + tid;
                    *(uint4*)(ldsb + (d4 >> 5) * 528 + (d4 & 31) * 16) = v[i];
                    pend &= ~(1u << i);
                }
        }
        __syncthreads();   // staging complete (only barrier in the step)

        // C: A-fragments from LDS + MFMA (weights in registers)
        const unsigned short (*hl)[Hsz + 8] = h_lds[s & 1];
        f32x4 acc0 = {0.f,0.f,0.f,0.f}, acc1 = {0.f,0.f,0.f,0.f};
        if (s < Ssz) {
            #pragma unroll
            for (int kt = 0; kt < 8; ++kt) {
                int k0 = kt * 32 + q * 8;
                short8 a0 = *(const short8*)&hl[n][k0];
                short8 a1 = *(const short8*)&hl[16 + n][k0];
                acc0 = __builtin_amdgcn_mfma_f32_16x16x32_bf16(a0, be[kt], acc0, 0, 0, 0);
                acc1 = __builtin_amdgcn_mfma_f32_16x16x32_bf16(a1, be[kt], acc1, 0, 0, 0);
            }
        } else {
            #pragma unroll
            for (int kt = 0; kt < 8; ++kt) {
                int k0 = kt * 32 + q * 8;
                short8 a0 = *(const short8*)&hl[n][k0];
                short8 a1 = *(const short8*)&hl[16 + n][k0];
                acc0 = __builtin_amdgcn_mfma_f32_16x16x32_bf16(a0, bd[kt], acc0, 0, 0, 0);
                acc1 = __builtin_amdgcn_mfma_f32_16x16x32_bf16(a1, bd[kt], acc1, 0, 0, 0);
            }
        }

        // D: wave-private transpose (write own C layout, read own cells).
        #pragma unroll
        for (int r = 0; r < 4; ++r) {
            glds[w][n][4 * q + r]      = acc0[r];
            glds[w][n][16 + 4 * q + r] = acc1[r];
        }
        asm volatile("s_waitcnt lgkmcnt(0)" ::: "memory");   // same-wave W->R
        __builtin_amdgcn_sched_barrier(0);

        float ai0 = glds[w][4 * c0 + 0][m] + xg0.x, ai1 = glds[w][4 * c0 + 4][m] + xg0.y;
        float af0 = glds[w][4 * c0 + 1][m] + xg1.x, af1 = glds[w][4 * c0 + 5][m] + xg1.y;
        float ag0 = glds[w][4 * c0 + 2][m] + xg2.x, ag1 = glds[w][4 * c0 + 6][m] + xg2.y;
        float ao0 = glds[w][4 * c0 + 3][m] + xg3.x, ao1 = glds[w][4 * c0 + 7][m] + xg3.y;
        cc0 = sigm(af0) * cc0 + sigm(ai0) * tanh_fast(ag0);
        cc1 = sigm(af1) * cc1 + sigm(ai1) * tanh_fast(ag1);
        float h0 = sigm(ao0) * tanh_fast(cc0);
        float h1 = sigm(ao1) * tanh_fast(cc1);

        // E: dual-publish h_{s+1} and proceed (no drain, no flag)
        unsigned pk = (unsigned)f2bf(h0) | ((unsigned)f2bf(h1) << 16);
        const long hidx = (long)(s + 1) * 4096 + m * 128 + (jc >> 1);
        hF[hidx] = pk;                                   // plain -> shared L2
        __hip_atomic_store(&hS[hidx], pk, __ATOMIC_RELAXED, __HIP_MEMORY_SCOPE_AGENT);

        // off the critical path: history + final state
        if (s >= Ssz)
            hs_dw[((long)(s - Ssz) * Bsz + m) * 128 + (jc >> 1)] = pk;
        if (s == NSTEP - 1) {
            *(float2*)&out_tail[m * Hsz + jc]             = make_float2(h0, h1);
            *(float2*)&out_tail[Bsz * Hsz + m * Hsz + jc] = make_float2(cc0, cc1);
        }
    }
}

// ---------------------------------------------------------------------------
// K3: projection out[b][td+1][v] = hs[td][b][:] @ Wfc[v][:] + bfc[v]
// grid (125, 63): x = 256-col slice of V, y = decoder step. bf16 MFMA.
// ---------------------------------------------------------------------------
__global__ void __launch_bounds__(256) k_proj(
        const unsigned short* __restrict__ hs, const unsigned short* __restrict__ WfcB,
        const float* __restrict__ bfc, float* __restrict__ out) {
    const int vb = blockIdx.x;    // 0..124
    const int td = blockIdx.y;    // 0..62
    const int tid = threadIdx.x, w = tid >> 6, l = tid & 63, n = l & 15, q = l >> 4;

    __shared__ unsigned short a_lds[32][Hsz + 8];     // 16.5 KB
    __shared__ unsigned short b_lds[256][Hsz + 8];    // 132 KB

    {   // stage A: hs rows for this td (contiguous 16 KB)
        int b = tid >> 3, seg = tid & 7;
        const uint4* g = (const uint4*)(hs + ((long)td * Bsz + b) * Hsz);
        #pragma unroll
        for (int i = 0; i < 4; ++i)
            *(uint4*)&a_lds[b][i * 64 + seg * 8] = g[i * 8 + seg];
    }
    {   // stage B tile: 128 KB contiguous from WfcB, remapped into padded rows
        const uint4* g = (const uint4*)(WfcB + (long)vb * 256 * Hsz);
        #pragma unroll 4
        for (int i = 0; i < 32; ++i) {
            int u = i * 256 + tid;           // uint4 index (8 bf16 each)
            int row = u >> 5;
            int kk = (u & 31) * 8;
            *(uint4*)&b_lds[row][kk] = g[u];
        }
    }
    __syncthreads();

    short8 af[2][8];
    #pragma unroll
    for (int kt = 0; kt < 8; ++kt) {
        int k0 = kt * 32 + q * 8;
        af[0][kt] = *(const short8*)&a_lds[n][k0];
        af[1][kt] = *(const short8*)&a_lds[16 + n][k0];
    }
    f32x4 acc[2][4];
    #pragma unroll
    for (int nt = 0; nt < 4; ++nt) { acc[0][nt] = (f32x4){0.f,0.f,0.f,0.f}; acc[1][nt] = (f32x4){0.f,0.f,0.f,0.f}; }

    #pragma unroll
    for (int nt = 0; nt < 4; ++nt) {
        int cl = w * 64 + nt * 16 + n;
        #pragma unroll
        for (int kt = 0; kt < 8; ++kt) {
            short8 bf = *(const short8*)&b_lds[cl][kt * 32 + q * 8];
            acc[0][nt] = __builtin_amdgcn_mfma_f32_16x16x32_bf16(af[0][kt], bf, acc[0][nt], 0, 0, 0);
            acc[1][nt] = __builtin_amdgcn_mfma_f32_16x16x32_bf16(af[1][kt], bf, acc[1][nt], 0, 0, 0);
        }
    }
    #pragma unroll
    for (int nt = 0; nt < 4; ++nt) {
        int col = vb * 256 + w * 64 + nt * 16 + n;
        float bv = bfc[col];
        #pragma unroll
        for (int mt = 0; mt < 2; ++mt) {
            #pragma unroll
            for (int r = 0; r < 4; ++r) {
                int b = mt * 16 + q * 4 + r;
                out[(long)b * (Tsz * Vsz) + (long)(td + 1) * Vsz + col] = acc[mt][nt][r] + bv;
            }
        }
    }
}

// ---------------------------------------------------------------------------
// K4: zero prediction slot t=0 (d_out is poisoned before every launch)
// ---------------------------------------------------------------------------
__global__ void k_zero0(float* __restrict__ out) {
    int i = blockIdx.x * 256 + threadIdx.x;    // 256000 float4s = 32*32000 floats
    int b = i / 8000;
    int c = i % 8000;
    ((float4*)(out + (long)b * (Tsz * Vsz)))[c] = make_float4(0.f, 0.f, 0.f, 0.f);
}

// ---------------------------------------------------------------------------
extern "C" void kernel_launch(void* const* d_in, const int* in_sizes, int n_in,
                              void* d_out, int out_size, void* d_ws, size_t ws_size,
                              hipStream_t stream) {
    const int*   src     = (const int*)d_in[0];
    const int*   trg     = (const int*)d_in[1];
    const float* emb_src = (const float*)d_in[2];
    const float* Wih_e   = (const float*)d_in[3];
    const float* Whh_e   = (const float*)d_in[4];
    const float* b_e     = (const float*)d_in[5];
    const float* emb_trg = (const float*)d_in[6];
    const float* Wih_d   = (const float*)d_in[7];
    const float* Whh_d   = (const float*)d_in[8];
    const float* b_d     = (const float*)d_in[9];
    const float* Wfc     = (const float*)d_in[10];
    const float* bfc     = (const float*)d_in[11];
    float* out = (float*)d_out;

    char* ws = (char*)d_ws;
    float*          xW   = (float*)ws;                          // 191*32*1024*4 = 25,034,752 B
    unsigned short* WfcB = (unsigned short*)(ws + 25034752);    // 32000*256*2  = 16,384,000 B
    unsigned short* hs   = (unsigned short*)(ws + 41418752);    // 63*32*256*2  =  1,032,192 B
    unsigned*       hF   = (unsigned*)(ws + 42450944);          // 192 slots x 16 KB = 3,145,728 B
    unsigned*       hS   = (unsigned*)(ws + 45596672);          // 192 slots x 16 KB = 3,145,728 B
    (void)ws_size;

    k_cvt<<<4000, 256, 0, stream>>>(Wfc, WfcB, 8192000L);
    k_input<<<dim3(16, 191), 256, 0, stream>>>(src, trg, emb_src, emb_trg,
                                               Wih_e, Wih_d, b_e, b_d, xW, hF, hS);
    k_recur<<<NBL, 256, 0, stream>>>(Whh_e, Whh_d, xW, hF, hS, (unsigned*)hs,
                                     out + 65536000L);
    k_zero0<<<1000, 256, 0, stream>>>(out);
    k_proj<<<dim3(125, 63), 256, 0, stream>>>(hs, WfcB, bfc, out);
}

// Round 4
// 1019.192 us; speedup vs baseline: 1.9809x; 1.9809x over previous
//
#include <hip/hip_runtime.h>
#include <hip/hip_bf16.h>

#define Bsz 32
#define Ssz 128
#define Tsz 64
#define TD  63           // decoder steps
#define NSTEP 191        // Ssz + TD
#define Esz 128
#define Hsz 256
#define G4  1024         // 4*H
#define Vsz 32000
#define NB  16           // recurrence blocks
#define SENT32 0xFFC1FFC1u   // 2x bf16 NaN — unreachable as packed h pair

typedef __attribute__((ext_vector_type(8))) short short8;
typedef __attribute__((ext_vector_type(4))) float f32x4;

__device__ __forceinline__ unsigned short f2bf(float f) {
    union { float f; unsigned u; } v; v.f = f;
    unsigned u = v.u;
    unsigned r = u + 0x7FFFu + ((u >> 16) & 1u);   // RNE
    return (unsigned short)(r >> 16);
}

__device__ __forceinline__ float rcpf(float x) { return __builtin_amdgcn_rcpf(x); }
__device__ __forceinline__ float sigm(float x) { return rcpf(1.f + __expf(-x)); }
// tanh(x) = 1 - 2/(e^{2x}+1); saturates correctly at +-inf
__device__ __forceinline__ float tanh_fast(float x) { return 1.f - 2.f * rcpf(1.f + __expf(2.f * x)); }

__device__ __forceinline__ bool has_sent(unsigned long long v) {
    return ((unsigned)v == SENT32) || ((unsigned)(v >> 32) == SENT32);
}

// ---------------------------------------------------------------------------
// K0: convert Wfc fp32 -> bf16 in workspace
// ---------------------------------------------------------------------------
__global__ void k_cvt(const float* __restrict__ src, unsigned short* __restrict__ dst, long n) {
    long i = (long)blockIdx.x * blockDim.x + threadIdx.x;
    long base = i * 8;
    if (base >= n) return;
    float4 f0 = ((const float4*)(src + base))[0];
    float4 f1 = ((const float4*)(src + base))[1];
    union { unsigned short u[8]; uint4 v; } r;
    r.u[0] = f2bf(f0.x); r.u[1] = f2bf(f0.y); r.u[2] = f2bf(f0.z); r.u[3] = f2bf(f0.w);
    r.u[4] = f2bf(f1.x); r.u[5] = f2bf(f1.y); r.u[6] = f2bf(f1.z); r.u[7] = f2bf(f1.w);
    *(uint4*)(dst + base) = r.v;
}

// ---------------------------------------------------------------------------
// K1: xW[t][b][g] = emb[token(t,b)] @ Wih^T + bias  for all 191 steps.
// grid (16, 191). Also initializes the h dataflow buffer: slot 0 = h_0
// zeros, slots 1..191 = SENTINEL. Agent-scope stores so k_recur's
// L2-bypassing loads see them (stream order guarantees completion first).
// ---------------------------------------------------------------------------
__global__ void __launch_bounds__(256) k_input(
        const int* __restrict__ src, const int* __restrict__ trg,
        const float* __restrict__ emb_src, const float* __restrict__ emb_trg,
        const float* __restrict__ Wih_e, const float* __restrict__ Wih_d,
        const float* __restrict__ b_e, const float* __restrict__ b_d,
        float* __restrict__ xW, unsigned* __restrict__ hbuf_dw) {
    const int t = blockIdx.y;
    const int nb = blockIdx.x;
    const int tid = threadIdx.x;
    const bool enc = (t < Ssz);
    const float* emb  = enc ? emb_src : emb_trg;
    const float* Wih  = enc ? Wih_e : Wih_d;
    const float* bias = enc ? b_e : b_d;

    __shared__ unsigned short a_lds[32][Esz + 8];   // [32][136] bf16

    {   // stage embedding rows (bf16) for the 32 batch elements
        int b = tid >> 3, seg = tid & 7;
        int tok = enc ? src[b * Ssz + t] : trg[b * Tsz + (t - Ssz)];
        const float* row = emb + (long)tok * Esz + seg * 16;
        #pragma unroll
        for (int i = 0; i < 16; ++i)
            a_lds[b][seg * 16 + i] = f2bf(row[i]);
    }
    // sentinel-fill slot t+1 (16 blocks x 256 threads = 4096 dwords = 1 slot)
    __hip_atomic_store(&hbuf_dw[(t + 1) * 4096 + nb * 256 + tid], SENT32,
                       __ATOMIC_RELAXED, __HIP_MEMORY_SCOPE_AGENT);
    if (t == 0) {
        // slot 0 (h_0 = zeros): 4096 dwords
        __hip_atomic_store(&hbuf_dw[nb * 256 + tid], 0u, __ATOMIC_RELAXED,
                           __HIP_MEMORY_SCOPE_AGENT);
    }
    __syncthreads();

    const int w = tid >> 6, l = tid & 63;
    const int n = l & 15, q = l >> 4;
    const int col = nb * 64 + w * 16 + n;           // 0..1023

    short8 bw[4];
    #pragma unroll
    for (int kt = 0; kt < 4; ++kt) {
        const float* wr = Wih + (long)col * Esz + kt * 32 + q * 8;
        short8 f;
        #pragma unroll
        for (int i = 0; i < 8; ++i) f[i] = (short)f2bf(wr[i]);
        bw[kt] = f;
    }
    f32x4 acc0 = {0.f,0.f,0.f,0.f}, acc1 = {0.f,0.f,0.f,0.f};
    #pragma unroll
    for (int kt = 0; kt < 4; ++kt) {
        int k0 = kt * 32 + q * 8;
        short8 a0 = *(const short8*)&a_lds[n][k0];
        short8 a1 = *(const short8*)&a_lds[16 + n][k0];
        acc0 = __builtin_amdgcn_mfma_f32_16x16x32_bf16(a0, bw[kt], acc0, 0, 0, 0);
        acc1 = __builtin_amdgcn_mfma_f32_16x16x32_bf16(a1, bw[kt], acc1, 0, 0, 0);
    }
    float bv = bias[col];
    float* o = xW + (long)t * (Bsz * G4);
    #pragma unroll
    for (int r = 0; r < 4; ++r) {
        int m = q * 4 + r;
        o[m * G4 + col]        = acc0[r] + bv;
        o[(16 + m) * G4 + col] = acc1[r] + bv;
    }
}

// ---------------------------------------------------------------------------
// K2: LSTM recurrence, 191 steps, 16 blocks — sentinel-slot dataflow with
// BATCHED retry (the r2->r4 fix).
//
// Protocol: hbuf has 192 per-step slots (u16 [192][32][256]); slot 0 = h_0
// zeros, slots 1.. pre-filled with bf16-NaN sentinel by k_input. Consumers
// coalesced-stage slot s into LDS via agent-scope (L2-bypass) u64 loads;
// retry is BATCHED: each round re-issues ALL still-sentinel loads together,
// so a round costs ~1 L3 RTT regardless of pending count (r2's per-element
// serial retry cost up to 8 dependent RTTs/step — that was the whole gap).
// Producers store h_{s+1} dwords (relaxed agent scope) and proceed — no
// drains, no flags. Slots never reused -> no ABA; stores monotone -> no
// livelock. h values are sigm*tanh products (always finite) -> never equal
// the NaN sentinel; each dword is one producer's store -> no tearing.
//
// h_lds is double-buffered -> ONE barrier per step: barrier(s+1) is
// program-ordered after every wave's ds_read(s), so staging(s+2) (same
// buffer as s) cannot start until all waves finished reading step s.
//
// Compute: wave-local gate packing (wave w's B operand packs gate-col
// n = 4p+g -> Whh row g*256 + (nb*16 + 4w + p)); gate transpose is
// wave-private (lgkmcnt(0) + sched_barrier, no block barrier).
// ---------------------------------------------------------------------------
__global__ void __launch_bounds__(256, 1) k_recur(
        const float* __restrict__ Whh_e, const float* __restrict__ Whh_d,
        const float* __restrict__ xW, unsigned* __restrict__ hbuf_dw,
        unsigned* __restrict__ hs_dw, float* __restrict__ out_tail) {
    const int nb = blockIdx.x, tid = threadIdx.x;
    const int w = tid >> 6, l = tid & 63;
    const int n = l & 15, q = l >> 4;          // MFMA lane coords
    const int p = (l >> 2) & 3, g = l & 3;     // gate-col n = 4*p + g
    const int JB = nb * 16 + w * 4;            // wave's h-columns JB..JB+3

    __shared__ unsigned short h_lds[2][32][Hsz + 8];  // dbuf, row = 528 B
    __shared__ float glds[4][16][35];                 // wave-private transpose

    // Weights in registers: B fragment for gate-col n=(p,g) = Whh row g*256+JB+p
    short8 be[8], bd[8];
    {
        const int R = g * Hsz + JB + p;
        #pragma unroll
        for (int kt = 0; kt < 8; ++kt) {
            const float* we = Whh_e + (long)R * Hsz + kt * 32 + q * 8;
            const float* wd = Whh_d + (long)R * Hsz + kt * 32 + q * 8;
            short8 fe, fd;
            #pragma unroll
            for (int i = 0; i < 8; ++i) { fe[i] = (short)f2bf(we[i]); fd[i] = (short)f2bf(wd[i]); }
            be[kt] = fe; bd[kt] = fd;
        }
    }

    // pointwise cells: lane handles (batch m, cols jc, jc+1); jc even.
    const int m = l >> 1, c0 = (l & 1) * 2, jc = JB + c0;
    float cc0 = 0.f, cc1 = 0.f;

    for (int s = 0; s < NSTEP; ++s) {
        // A: prefetch this lane's x-gates (independent of h; overlaps the poll)
        const float* xrow = xW + (long)s * (Bsz * G4) + m * G4 + jc;
        float2 xg0 = *(const float2*)(xrow + 0 * Hsz);
        float2 xg1 = *(const float2*)(xrow + 1 * Hsz);
        float2 xg2 = *(const float2*)(xrow + 2 * Hsz);
        float2 xg3 = *(const float2*)(xrow + 3 * Hsz);

        // B: poll-stage h_s (slot s) into h_lds[s&1], BATCHED retry.
        {
            const unsigned long long* hp =
                (const unsigned long long*)hbuf_dw + (long)s * 2048;
            char* const ldsb = (char*)&h_lds[s & 1][0][0];
            unsigned long long v[8];
            unsigned pend = 0xFFu;
            do {
                #pragma unroll
                for (int i = 0; i < 8; ++i)
                    if (pend & (1u << i))
                        v[i] = __hip_atomic_load(hp + i * 256 + tid, __ATOMIC_RELAXED,
                                                 __HIP_MEMORY_SCOPE_AGENT);
                #pragma unroll
                for (int i = 0; i < 8; ++i)
                    if ((pend & (1u << i)) && !has_sent(v[i])) {
                        int d2 = i * 256 + tid;          // u64 index, 4 bf16 each
                        *(unsigned long long*)(ldsb + (d2 >> 6) * 528 + (d2 & 63) * 8) = v[i];
                        pend &= ~(1u << i);
                    }
            } while (__builtin_expect(pend != 0, 0));
        }
        __syncthreads();   // staging complete — ONLY barrier in the step

        // C: A-fragments from LDS + MFMA (weights in registers)
        const unsigned short (*hl)[Hsz + 8] = h_lds[s & 1];
        f32x4 acc0 = {0.f,0.f,0.f,0.f}, acc1 = {0.f,0.f,0.f,0.f};
        if (s < Ssz) {
            #pragma unroll
            for (int kt = 0; kt < 8; ++kt) {
                int k0 = kt * 32 + q * 8;
                short8 a0 = *(const short8*)&hl[n][k0];
                short8 a1 = *(const short8*)&hl[16 + n][k0];
                acc0 = __builtin_amdgcn_mfma_f32_16x16x32_bf16(a0, be[kt], acc0, 0, 0, 0);
                acc1 = __builtin_amdgcn_mfma_f32_16x16x32_bf16(a1, be[kt], acc1, 0, 0, 0);
            }
        } else {
            #pragma unroll
            for (int kt = 0; kt < 8; ++kt) {
                int k0 = kt * 32 + q * 8;
                short8 a0 = *(const short8*)&hl[n][k0];
                short8 a1 = *(const short8*)&hl[16 + n][k0];
                acc0 = __builtin_amdgcn_mfma_f32_16x16x32_bf16(a0, bd[kt], acc0, 0, 0, 0);
                acc1 = __builtin_amdgcn_mfma_f32_16x16x32_bf16(a1, bd[kt], acc1, 0, 0, 0);
            }
        }

        // D: wave-private transpose (write own C layout, read own cells).
        //    C layout: lane(q,n) reg r = C[batch 4q+r][gate-col n] (+16 acc1).
        #pragma unroll
        for (int r = 0; r < 4; ++r) {
            glds[w][n][4 * q + r]      = acc0[r];
            glds[w][n][16 + 4 * q + r] = acc1[r];
        }
        asm volatile("s_waitcnt lgkmcnt(0)" ::: "memory");   // same-wave W->R
        __builtin_amdgcn_sched_barrier(0);

        float ai0 = glds[w][4 * c0 + 0][m] + xg0.x, ai1 = glds[w][4 * c0 + 4][m] + xg0.y;
        float af0 = glds[w][4 * c0 + 1][m] + xg1.x, af1 = glds[w][4 * c0 + 5][m] + xg1.y;
        float ag0 = glds[w][4 * c0 + 2][m] + xg2.x, ag1 = glds[w][4 * c0 + 6][m] + xg2.y;
        float ao0 = glds[w][4 * c0 + 3][m] + xg3.x, ao1 = glds[w][4 * c0 + 7][m] + xg3.y;
        cc0 = sigm(af0) * cc0 + sigm(ai0) * tanh_fast(ag0);
        cc1 = sigm(af1) * cc1 + sigm(ai1) * tanh_fast(ag1);
        float h0 = sigm(ao0) * tanh_fast(cc0);
        float h1 = sigm(ao1) * tanh_fast(cc1);

        // E: publish h_{s+1} into slot s+1 and PROCEED (no drain, no flag)
        unsigned pk = (unsigned)f2bf(h0) | ((unsigned)f2bf(h1) << 16);
        __hip_atomic_store(hbuf_dw + (long)(s + 1) * 4096 + m * 128 + (jc >> 1),
                           pk, __ATOMIC_RELAXED, __HIP_MEMORY_SCOPE_AGENT);

        // off the critical path: history + final state (consumed post-kernel)
        if (s >= Ssz)
            hs_dw[((long)(s - Ssz) * Bsz + m) * 128 + (jc >> 1)] = pk;
        if (s == NSTEP - 1) {
            *(float2*)&out_tail[m * Hsz + jc]             = make_float2(h0, h1);
            *(float2*)&out_tail[Bsz * Hsz + m * Hsz + jc] = make_float2(cc0, cc1);
        }
    }
}

// ---------------------------------------------------------------------------
// K3: projection out[b][td+1][v] = hs[td][b][:] @ Wfc[v][:] + bfc[v]
// grid (125, 63): x = 256-col slice of V, y = decoder step. bf16 MFMA.
// ---------------------------------------------------------------------------
__global__ void __launch_bounds__(256) k_proj(
        const unsigned short* __restrict__ hs, const unsigned short* __restrict__ WfcB,
        const float* __restrict__ bfc, float* __restrict__ out) {
    const int vb = blockIdx.x;    // 0..124
    const int td = blockIdx.y;    // 0..62
    const int tid = threadIdx.x, w = tid >> 6, l = tid & 63, n = l & 15, q = l >> 4;

    __shared__ unsigned short a_lds[32][Hsz + 8];     // 16.5 KB
    __shared__ unsigned short b_lds[256][Hsz + 8];    // 132 KB

    {   // stage A: hs rows for this td (contiguous 16 KB)
        int b = tid >> 3, seg = tid & 7;
        const uint4* g = (const uint4*)(hs + ((long)td * Bsz + b) * Hsz);
        #pragma unroll
        for (int i = 0; i < 4; ++i)
            *(uint4*)&a_lds[b][i * 64 + seg * 8] = g[i * 8 + seg];
    }
    {   // stage B tile: 128 KB contiguous from WfcB, remapped into padded rows
        const uint4* g = (const uint4*)(WfcB + (long)vb * 256 * Hsz);
        #pragma unroll 4
        for (int i = 0; i < 32; ++i) {
            int u = i * 256 + tid;           // uint4 index (8 bf16 each)
            int row = u >> 5;
            int kk = (u & 31) * 8;
            *(uint4*)&b_lds[row][kk] = g[u];
        }
    }
    __syncthreads();

    short8 af[2][8];
    #pragma unroll
    for (int kt = 0; kt < 8; ++kt) {
        int k0 = kt * 32 + q * 8;
        af[0][kt] = *(const short8*)&a_lds[n][k0];
        af[1][kt] = *(const short8*)&a_lds[16 + n][k0];
    }
    f32x4 acc[2][4];
    #pragma unroll
    for (int nt = 0; nt < 4; ++nt) { acc[0][nt] = (f32x4){0.f,0.f,0.f,0.f}; acc[1][nt] = (f32x4){0.f,0.f,0.f,0.f}; }

    #pragma unroll
    for (int nt = 0; nt < 4; ++nt) {
        int cl = w * 64 + nt * 16 + n;
        #pragma unroll
        for (int kt = 0; kt < 8; ++kt) {
            short8 bf = *(const short8*)&b_lds[cl][kt * 32 + q * 8];
            acc[0][nt] = __builtin_amdgcn_mfma_f32_16x16x32_bf16(af[0][kt], bf, acc[0][nt], 0, 0, 0);
            acc[1][nt] = __builtin_amdgcn_mfma_f32_16x16x32_bf16(af[1][kt], bf, acc[1][nt], 0, 0, 0);
        }
    }
    #pragma unroll
    for (int nt = 0; nt < 4; ++nt) {
        int col = vb * 256 + w * 64 + nt * 16 + n;
        float bv = bfc[col];
        #pragma unroll
        for (int mt = 0; mt < 2; ++mt) {
            #pragma unroll
            for (int r = 0; r < 4; ++r) {
                int b = mt * 16 + q * 4 + r;
                out[(long)b * (Tsz * Vsz) + (long)(td + 1) * Vsz + col] = acc[mt][nt][r] + bv;
            }
        }
    }
}

// ---------------------------------------------------------------------------
// K4: zero prediction slot t=0 (d_out is poisoned before every launch)
// ---------------------------------------------------------------------------
__global__ void k_zero0(float* __restrict__ out) {
    int i = blockIdx.x * 256 + threadIdx.x;    // 256000 float4s = 32*32000 floats
    int b = i / 8000;
    int c = i % 8000;
    ((float4*)(out + (long)b * (Tsz * Vsz)))[c] = make_float4(0.f, 0.f, 0.f, 0.f);
}

// ---------------------------------------------------------------------------
extern "C" void kernel_launch(void* const* d_in, const int* in_sizes, int n_in,
                              void* d_out, int out_size, void* d_ws, size_t ws_size,
                              hipStream_t stream) {
    const int*   src     = (const int*)d_in[0];
    const int*   trg     = (const int*)d_in[1];
    const float* emb_src = (const float*)d_in[2];
    const float* Wih_e   = (const float*)d_in[3];
    const float* Whh_e   = (const float*)d_in[4];
    const float* b_e     = (const float*)d_in[5];
    const float* emb_trg = (const float*)d_in[6];
    const float* Wih_d   = (const float*)d_in[7];
    const float* Whh_d   = (const float*)d_in[8];
    const float* b_d     = (const float*)d_in[9];
    const float* Wfc     = (const float*)d_in[10];
    const float* bfc     = (const float*)d_in[11];
    float* out = (float*)d_out;

    char* ws = (char*)d_ws;
    float*          xW   = (float*)ws;                          // 191*32*1024*4 = 25,034,752 B
    unsigned short* WfcB = (unsigned short*)(ws + 25034752);    // 32000*256*2  = 16,384,000 B
    unsigned short* hs   = (unsigned short*)(ws + 41418752);    // 63*32*256*2  =  1,032,192 B
    unsigned*       hbuf = (unsigned*)(ws + 42450944);          // 192 slots x 16 KB = 3,145,728 B
    (void)ws_size;

    k_cvt<<<4000, 256, 0, stream>>>(Wfc, WfcB, 8192000L);
    k_input<<<dim3(16, 191), 256, 0, stream>>>(src, trg, emb_src, emb_trg,
                                               Wih_e, Wih_d, b_e, b_d, xW, hbuf);
    k_recur<<<NB, 256, 0, stream>>>(Whh_e, Whh_d, xW, hbuf, (unsigned*)hs,
                                    out + 65536000L);
    k_zero0<<<1000, 256, 0, stream>>>(out);
    k_proj<<<dim3(125, 63), 256, 0, stream>>>(hs, WfcB, bfc, out);
}